// Round 5
// baseline (113.060 us; speedup 1.0000x reference)
//
#include <hip/hip_runtime.h>

#define SLOPE 0.01f

typedef __attribute__((ext_vector_type(8))) short short8;
typedef __attribute__((ext_vector_type(4))) float f32x4;

__device__ __forceinline__ float lrelu(float v) { return v >= 0.f ? v : SLOPE * v; }

__device__ __forceinline__ unsigned short f2bf(float f) {
    union { float f; unsigned int u; } v; v.f = f;
    unsigned int r = v.u + 0x7fffu + ((v.u >> 16) & 1u);
    return (unsigned short)(r >> 16);
}
__device__ __forceinline__ float bf2f(unsigned short h) {
    union { unsigned int u; float f; } v; v.u = ((unsigned int)h) << 16;
    return v.f;
}

// ---------------------------------------------------------------------------
// Workspace layout (f32 slot offsets):
//   P2   bf16 [ph=4][A=25][B=25][ic=128]   @ 0       (160000 f32 slots)
//   Z2   bf16 [ph=4][A=21][B=21][oc=128]   @ 160000  (112896)
//   W2   bf16 [oc=128][kpos=25][ic=128]    @ 272896  (204800)
//   W3   bf16 [oc=128][kpos=25][ic=128]    @ 477696  (204800)
//   C4B  bf16 [256][128]                   @ 682496  (16384)
//   C5B  bf16 [128][256]                   @ 698880  (16384)
//   DWB  bf16 [512][128]                   @ 715264  (32768)
// MFMA k-order for conv2/conv3: k = kpos*128 + ic
// ---------------------------------------------------------------------------

// K1: [0,1250) fused conv1+pool1 -> P2. [1250,1506) W2/W3 transpose.
//     [1506,2018) bf16 casts of c4w/c5w/dw.
__global__ __launch_bounds__(256) void k_front(const float* __restrict__ x,
                                               const float* __restrict__ c1w,
                                               const float* __restrict__ c1b,
                                               const float* __restrict__ c2w,
                                               const float* __restrict__ c3w,
                                               const float* __restrict__ c4w,
                                               const float* __restrict__ c5w,
                                               const float* __restrict__ dw,
                                               unsigned short* __restrict__ P2,
                                               unsigned short* __restrict__ W2,
                                               unsigned short* __restrict__ W3,
                                               unsigned short* __restrict__ C4B,
                                               unsigned short* __restrict__ C5B,
                                               unsigned short* __restrict__ DWB) {
    __shared__ float smem[9600];
    int bid = blockIdx.x, tid = threadIdx.x;

    if (bid < 1250) {
        for (int idx = tid; idx < 9600; idx += 256) smem[idx] = c1w[idx];
        __syncthreads();

        int t = bid * 256 + tid;          // [0, 320000)
        int ic = t & 127;
        int rest = t >> 7;
        int B = rest % 25;
        int A = (rest / 25) % 25;
        int ph = rest / 625;
        int py = ph >> 1, px = ph & 1;
        int r0 = 2 * A + py, s0 = 2 * B + px;

        float a00 = 0.f, a01 = 0.f, a10 = 0.f, a11 = 0.f;
        const float* lw = smem + ic * 75;
        for (int c = 0; c < 3; ++c) {
            const float* xc = x + c * 576;
            const float* lwc = lw + c * 25;
#pragma unroll
            for (int ky = 0; ky < 5; ++ky) {
                int iy = r0 + ky - 16;
                bool v0 = (iy >= 0) && (iy < 24);
                bool v1 = (iy + 1 >= 0) && (iy + 1 < 24);
                if (!v0 && !v1) continue;
#pragma unroll
                for (int kx = 0; kx < 5; ++kx) {
                    int ix = s0 + kx - 16;
                    float w = lwc[ky * 5 + kx];
                    bool u0 = (ix >= 0) && (ix < 24);
                    bool u1 = (ix + 1 >= 0) && (ix + 1 < 24);
                    float x00 = (v0 && u0) ? xc[iy * 24 + ix] : 0.f;
                    float x01 = (v0 && u1) ? xc[iy * 24 + ix + 1] : 0.f;
                    float x10 = (v1 && u0) ? xc[(iy + 1) * 24 + ix] : 0.f;
                    float x11 = (v1 && u1) ? xc[(iy + 1) * 24 + ix + 1] : 0.f;
                    a00 += x00 * w; a01 += x01 * w; a10 += x10 * w; a11 += x11 * w;
                }
            }
        }
        float mx = fmaxf(fmaxf(a00, a01), fmaxf(a10, a11));
        P2[t] = f2bf(lrelu(c1b[ic] + mx));
    } else if (bid < 1506) {
        int wbid = bid - 1250;            // 0..255
        const float* src = (wbid < 128) ? (c2w + wbid * 3200) : (c3w + (wbid - 128) * 3200);
        unsigned short* dst = (wbid < 128) ? (W2 + wbid * 3200) : (W3 + (wbid - 128) * 3200);
        for (int idx = tid; idx < 3200; idx += 256) smem[idx] = src[idx];
        __syncthreads();
        for (int idx = tid; idx < 3200; idx += 256) {
            int ic = idx & 127, kpos = idx >> 7;
            dst[idx] = f2bf(smem[ic * 25 + kpos]);
        }
    } else {
        int e = (bid - 1506) * 256 + tid;   // [0, 131072)
        if (e < 32768)        C4B[e] = f2bf(c4w[e]);
        else if (e < 65536)   C5B[e - 32768] = f2bf(c5w[e - 32768]);
        else                  DWB[e - 65536] = f2bf(dw[e - 65536]);
    }
}

// K2: conv2 via MFMA (validated) -> Z2[ph][A][B][oc]
__global__ __launch_bounds__(256) void k_conv2(const unsigned short* __restrict__ P2,
                                               const unsigned short* __restrict__ W2,
                                               const float* __restrict__ bias,
                                               unsigned short* __restrict__ Z2) {
    int bid = blockIdx.x;          // 168 = 4ph * 21A * 2oh
    int ph = bid / 42;
    int rem = bid % 42;
    int A = rem >> 1;
    int oh = rem & 1;
    int tid = threadIdx.x, lane = tid & 63, wid = tid >> 6;
    int m = lane & 15, bq = lane >> 4;
    int oc0 = oh * 64 + wid * 16;
    const unsigned short* wbase = W2 + (oc0 + m) * 3200 + 8 * bq;
    const unsigned short* pbase = P2 + ((ph * 25 + A) * 25) * 128 + 8 * bq;
    f32x4 acc0 = {0.f, 0.f, 0.f, 0.f}, acc1 = {0.f, 0.f, 0.f, 0.f};
    for (int kpos = 0; kpos < 25; ++kpos) {
        int ky = kpos / 5, kx = kpos % 5;
        const unsigned short* wp = wbase + kpos * 128;
        const unsigned short* p0 = pbase + (ky * 25 + m + kx) * 128;
        const unsigned short* p1 = p0 + 5 * 128;
#pragma unroll
        for (int ic0 = 0; ic0 < 128; ic0 += 32) {
            short8 a  = *(const short8*)(wp + ic0);
            short8 b0 = *(const short8*)(p0 + ic0);
            short8 b1 = *(const short8*)(p1 + ic0);
            acc0 = __builtin_amdgcn_mfma_f32_16x16x32_bf16(a, b0, acc0, 0, 0, 0);
            acc1 = __builtin_amdgcn_mfma_f32_16x16x32_bf16(a, b1, acc1, 0, 0, 0);
        }
    }
    int ocb = oc0 + 4 * bq;
    float b0v = bias[ocb], b1v = bias[ocb + 1], b2v = bias[ocb + 2], b3v = bias[ocb + 3];
    unsigned short* zrow = Z2 + ((ph * 21 + A) * 21) * 128 + ocb;
    {
        ushort4 pk;
        pk.x = f2bf(lrelu(acc0.x + b0v));
        pk.y = f2bf(lrelu(acc0.y + b1v));
        pk.z = f2bf(lrelu(acc0.z + b2v));
        pk.w = f2bf(lrelu(acc0.w + b3v));
        *(ushort4*)(zrow + m * 128) = pk;          // B = m (0..15)
    }
    if (m >= 11) {                                 // B = m+5 (16..20)
        ushort4 pk;
        pk.x = f2bf(lrelu(acc1.x + b0v));
        pk.y = f2bf(lrelu(acc1.y + b1v));
        pk.z = f2bf(lrelu(acc1.z + b2v));
        pk.w = f2bf(lrelu(acc1.w + b3v));
        *(ushort4*)(zrow + (m + 5) * 128) = pk;
    }
}

// K3: fused pool2 + conv3 + conv4 + conv5 + dense, all MFMA.
// 36 blocks x 512 threads (8 waves), 16 patches per block.
#define QSTR 3208
__global__ __launch_bounds__(512) void k_fuse3(const unsigned short* __restrict__ Z2,
                                               const unsigned short* __restrict__ W3,
                                               const float* __restrict__ c3b,
                                               const unsigned short* __restrict__ C4B,
                                               const float* __restrict__ c4b,
                                               const unsigned short* __restrict__ C5B,
                                               const float* __restrict__ c5b,
                                               const unsigned short* __restrict__ DWB,
                                               const float* __restrict__ db,
                                               float* __restrict__ out) {
    __shared__ unsigned short Qw[16 * QSTR];    // 16 patch windows [kpos=25][ic=128]
    __shared__ unsigned short h3bf[16 * 136];
    __shared__ unsigned short h4bf[16 * 264];
    __shared__ unsigned short h5bf[16 * 136];

    int bid = blockIdx.x, tid = threadIdx.x;
    int n0 = bid * 16;
    int lane = tid & 63, w = tid >> 6;          // 8 waves
    int m = lane & 15, bq = lane >> 4;

    // ---- phase A: pool2 gather into LDS ----
    for (int q = tid; q < 51200; q += 512) {
        int p = q / 3200;
        int rem = q - p * 3200;
        int kpos = rem >> 7, ic = rem & 127;
        int e = kpos / 5, f = kpos % 5;
        int n = n0 + p, i = n / 24, j = n % 24;
        int ph1 = (i & 1) * 2 + (j & 1);
        int C = (i >> 2) + e, D = (j >> 2) + f;
        int r0 = 2 * C + ((i >> 1) & 1), s0 = 2 * D + ((j >> 1) & 1);
        const unsigned short* z = Z2 + ((ph1 * 21 + r0) * 21 + s0) * 128 + ic;
        float m0 = fmaxf(bf2f(z[0]), bf2f(z[128]));
        float m1 = fmaxf(bf2f(z[21 * 128]), bf2f(z[22 * 128]));
        Qw[p * QSTR + rem] = f2bf(fmaxf(m0, m1));
    }
    __syncthreads();

    // ---- conv3: wave w -> oc tile [16w, 16w+16), cols = 16 patches ----
    {
        const unsigned short* wbase = W3 + (w * 16 + m) * 3200 + 8 * bq;
        const unsigned short* qbase = Qw + m * QSTR + 8 * bq;
        f32x4 acc = {0.f, 0.f, 0.f, 0.f};
        for (int kpos = 0; kpos < 25; ++kpos) {
            const unsigned short* wp = wbase + kpos * 128;
            const unsigned short* qp = qbase + kpos * 128;
#pragma unroll
            for (int ic0 = 0; ic0 < 128; ic0 += 32) {
                short8 a = *(const short8*)(wp + ic0);
                short8 b = *(const short8*)(qp + ic0);
                acc = __builtin_amdgcn_mfma_f32_16x16x32_bf16(a, b, acc, 0, 0, 0);
            }
        }
        int oc = w * 16 + bq * 4;
        float v0 = lrelu(acc.x + c3b[oc + 0]);
        float v1 = lrelu(acc.y + c3b[oc + 1]);
        float v2 = lrelu(acc.z + c3b[oc + 2]);
        float v3 = lrelu(acc.w + c3b[oc + 3]);
        uint2 pk;
        pk.x = (unsigned)f2bf(v0) | ((unsigned)f2bf(v1) << 16);
        pk.y = (unsigned)f2bf(v2) | ((unsigned)f2bf(v3) << 16);
        *(uint2*)(&h3bf[m * 136 + oc]) = pk;
    }
    __syncthreads();

    // ---- conv4: wave w -> oc tiles {32w, 32w+16}, K=128 ----
    {
        f32x4 acc[2] = {{0,0,0,0},{0,0,0,0}};
#pragma unroll
        for (int t = 0; t < 2; ++t) {
            const unsigned short* abase = C4B + (w * 32 + t * 16 + m) * 128 + 8 * bq;
#pragma unroll
            for (int k0 = 0; k0 < 128; k0 += 32) {
                short8 a = *(const short8*)(abase + k0);
                short8 b = *(const short8*)(&h3bf[m * 136 + k0 + 8 * bq]);
                acc[t] = __builtin_amdgcn_mfma_f32_16x16x32_bf16(a, b, acc[t], 0, 0, 0);
            }
        }
#pragma unroll
        for (int t = 0; t < 2; ++t) {
            int oc = w * 32 + t * 16 + bq * 4;
            float v0 = lrelu(acc[t].x + c4b[oc + 0]);
            float v1 = lrelu(acc[t].y + c4b[oc + 1]);
            float v2 = lrelu(acc[t].z + c4b[oc + 2]);
            float v3 = lrelu(acc[t].w + c4b[oc + 3]);
            uint2 pk;
            pk.x = (unsigned)f2bf(v0) | ((unsigned)f2bf(v1) << 16);
            pk.y = (unsigned)f2bf(v2) | ((unsigned)f2bf(v3) << 16);
            *(uint2*)(&h4bf[m * 264 + oc]) = pk;
        }
    }
    __syncthreads();

    // ---- conv5: wave w -> oc tile [16w, 16w+16), K=256 ----
    {
        const unsigned short* abase = C5B + (w * 16 + m) * 256 + 8 * bq;
        f32x4 acc = {0.f, 0.f, 0.f, 0.f};
#pragma unroll
        for (int k0 = 0; k0 < 256; k0 += 32) {
            short8 a = *(const short8*)(abase + k0);
            short8 b = *(const short8*)(&h4bf[m * 264 + k0 + 8 * bq]);
            acc = __builtin_amdgcn_mfma_f32_16x16x32_bf16(a, b, acc, 0, 0, 0);
        }
        int oc = w * 16 + bq * 4;
        float v0 = lrelu(acc.x + c5b[oc + 0]);
        float v1 = lrelu(acc.y + c5b[oc + 1]);
        float v2 = lrelu(acc.z + c5b[oc + 2]);
        float v3 = lrelu(acc.w + c5b[oc + 3]);
        uint2 pk;
        pk.x = (unsigned)f2bf(v0) | ((unsigned)f2bf(v1) << 16);
        pk.y = (unsigned)f2bf(v2) | ((unsigned)f2bf(v3) << 16);
        *(uint2*)(&h5bf[m * 136 + oc]) = pk;
    }
    __syncthreads();

    // ---- dense: wave w -> oc tiles {64w + 16t}, K=128, no activation ----
    {
        f32x4 acc[4] = {{0,0,0,0},{0,0,0,0},{0,0,0,0},{0,0,0,0}};
#pragma unroll
        for (int t = 0; t < 4; ++t) {
            const unsigned short* abase = DWB + (w * 64 + t * 16 + m) * 128 + 8 * bq;
#pragma unroll
            for (int k0 = 0; k0 < 128; k0 += 32) {
                short8 a = *(const short8*)(abase + k0);
                short8 b = *(const short8*)(&h5bf[m * 136 + k0 + 8 * bq]);
                acc[t] = __builtin_amdgcn_mfma_f32_16x16x32_bf16(a, b, acc[t], 0, 0, 0);
            }
        }
#pragma unroll
        for (int t = 0; t < 4; ++t) {
            int oc = w * 64 + t * 16 + bq * 4;
            out[(oc + 0) * 576 + n0 + m] = acc[t].x + db[oc + 0];
            out[(oc + 1) * 576 + n0 + m] = acc[t].y + db[oc + 1];
            out[(oc + 2) * 576 + n0 + m] = acc[t].z + db[oc + 2];
            out[(oc + 3) * 576 + n0 + m] = acc[t].w + db[oc + 3];
        }
    }
}

extern "C" void kernel_launch(void* const* d_in, const int* in_sizes, int n_in,
                              void* d_out, int out_size, void* d_ws, size_t ws_size,
                              hipStream_t stream) {
    const float* x   = (const float*)d_in[0];
    const float* c1w = (const float*)d_in[1];
    const float* c1b = (const float*)d_in[2];
    const float* c2w = (const float*)d_in[3];
    const float* c2b = (const float*)d_in[4];
    const float* c3w = (const float*)d_in[5];
    const float* c3b = (const float*)d_in[6];
    const float* c4w = (const float*)d_in[7];
    const float* c4b = (const float*)d_in[8];
    const float* c5w = (const float*)d_in[9];
    const float* c5b = (const float*)d_in[10];
    const float* dw  = (const float*)d_in[11];
    const float* db  = (const float*)d_in[12];
    float* out = (float*)d_out;

    float* ws = (float*)d_ws;
    unsigned short* P2  = (unsigned short*)(ws);            // 160000 f32 slots
    unsigned short* Z2  = (unsigned short*)(ws + 160000);   // 112896
    unsigned short* W2  = (unsigned short*)(ws + 272896);   // 204800
    unsigned short* W3  = (unsigned short*)(ws + 477696);   // 204800
    unsigned short* C4B = (unsigned short*)(ws + 682496);   // 16384
    unsigned short* C5B = (unsigned short*)(ws + 698880);   // 16384
    unsigned short* DWB = (unsigned short*)(ws + 715264);   // 32768

    k_front<<<2018, 256, 0, stream>>>(x, c1w, c1b, c2w, c3w, c4w, c5w, dw,
                                      P2, W2, W3, C4B, C5B, DWB);
    k_conv2<<<168, 256, 0, stream>>>(P2, W2, c2b, Z2);
    k_fuse3<<<36, 512, 0, stream>>>(Z2, W3, c3b, C4B, c4b, C5B, c5b, DWB, db, out);
}

// Round 6
// 82.167 us; speedup vs baseline: 1.3760x; 1.3760x over previous
//
#include <hip/hip_runtime.h>

#define SLOPE 0.01f

typedef __attribute__((ext_vector_type(8))) short short8;
typedef __attribute__((ext_vector_type(4))) float f32x4;

__device__ __forceinline__ float lrelu(float v) { return v >= 0.f ? v : SLOPE * v; }

__device__ __forceinline__ unsigned short f2bf(float f) {
    union { float f; unsigned int u; } v; v.f = f;
    unsigned int r = v.u + 0x7fffu + ((v.u >> 16) & 1u);
    return (unsigned short)(r >> 16);
}
__device__ __forceinline__ float bf2f(unsigned short h) {
    union { unsigned int u; float f; } v; v.u = ((unsigned int)h) << 16;
    return v.f;
}

// Weight swizzle for MFMA A-fragments (16-oc tiles):
//   swz(oc, k; K) = (((oc>>4)*(K>>5) + (k>>5))*64 + ((k>>3)&3)*16 + (oc&15))*8 + (k&7)
// => a-fragment load for (octile t, k-block kb) at lane l is
//    *(short8*)(W + ((t*(K>>5) + kb)*64 + l)*8)   -- 1KB contiguous per wave.
__device__ __forceinline__ int swz(int oc, int k, int Kdiv32) {
    return (((oc >> 4) * Kdiv32 + (k >> 5)) * 64 + ((k >> 3) & 3) * 16 + (oc & 15)) * 8 + (k & 7);
}

// ---------------------------------------------------------------------------
// Workspace layout (f32 slot offsets):
//   P2   bf16 [ph=4][A=25][B=25][ic=128]   @ 0       (160000 f32 slots)
//   Z2   bf16 [ph=4][A=21][B=21][oc=128]   @ 160000  (112896)
//   W2s  bf16 swz K=3200                   @ 272896  (204800)
//   W3s  bf16 swz K=3200                   @ 477696  (204800)
//   C4Bs bf16 swz K=128  (256x128)         @ 682496  (16384)
//   C5Bs bf16 swz K=256  (128x256)         @ 698880  (16384)
//   DWBs bf16 swz K=128  (512x128)         @ 715264  (32768)
//   Q2   bf16 [qph=16][C=10][D=10][ic=128] @ 748032  (102400)
// conv2/conv3 k-order: k = kpos*128 + ic
// ---------------------------------------------------------------------------

// K1: [0,1250) fused conv1+pool1 -> P2. [1250,1506) W2/W3 swizzle-transpose.
//     [1506,2018) swizzled bf16 casts of c4w/c5w/dw.
__global__ __launch_bounds__(256) void k_front(const float* __restrict__ x,
                                               const float* __restrict__ c1w,
                                               const float* __restrict__ c1b,
                                               const float* __restrict__ c2w,
                                               const float* __restrict__ c3w,
                                               const float* __restrict__ c4w,
                                               const float* __restrict__ c5w,
                                               const float* __restrict__ dw,
                                               unsigned short* __restrict__ P2,
                                               unsigned short* __restrict__ W2s,
                                               unsigned short* __restrict__ W3s,
                                               unsigned short* __restrict__ C4Bs,
                                               unsigned short* __restrict__ C5Bs,
                                               unsigned short* __restrict__ DWBs) {
    __shared__ float smem[9600];
    int bid = blockIdx.x, tid = threadIdx.x;

    if (bid < 1250) {
        for (int idx = tid; idx < 9600; idx += 256) smem[idx] = c1w[idx];
        __syncthreads();

        int t = bid * 256 + tid;          // [0, 320000)
        int ic = t & 127;
        int rest = t >> 7;
        int B = rest % 25;
        int A = (rest / 25) % 25;
        int ph = rest / 625;
        int py = ph >> 1, px = ph & 1;
        int r0 = 2 * A + py, s0 = 2 * B + px;

        float a00 = 0.f, a01 = 0.f, a10 = 0.f, a11 = 0.f;
        const float* lw = smem + ic * 75;
        for (int c = 0; c < 3; ++c) {
            const float* xc = x + c * 576;
            const float* lwc = lw + c * 25;
#pragma unroll
            for (int ky = 0; ky < 5; ++ky) {
                int iy = r0 + ky - 16;
                bool v0 = (iy >= 0) && (iy < 24);
                bool v1 = (iy + 1 >= 0) && (iy + 1 < 24);
                if (!v0 && !v1) continue;
#pragma unroll
                for (int kx = 0; kx < 5; ++kx) {
                    int ix = s0 + kx - 16;
                    float w = lwc[ky * 5 + kx];
                    bool u0 = (ix >= 0) && (ix < 24);
                    bool u1 = (ix + 1 >= 0) && (ix + 1 < 24);
                    float x00 = (v0 && u0) ? xc[iy * 24 + ix] : 0.f;
                    float x01 = (v0 && u1) ? xc[iy * 24 + ix + 1] : 0.f;
                    float x10 = (v1 && u0) ? xc[(iy + 1) * 24 + ix] : 0.f;
                    float x11 = (v1 && u1) ? xc[(iy + 1) * 24 + ix + 1] : 0.f;
                    a00 += x00 * w; a01 += x01 * w; a10 += x10 * w; a11 += x11 * w;
                }
            }
        }
        float mx = fmaxf(fmaxf(a00, a01), fmaxf(a10, a11));
        P2[t] = f2bf(lrelu(c1b[ic] + mx));
    } else if (bid < 1506) {
        int wbid = bid - 1250;            // 0..255
        int oc = wbid & 127;
        const float* src = (wbid < 128) ? (c2w + oc * 3200) : (c3w + oc * 3200);
        unsigned short* dst = (wbid < 128) ? W2s : W3s;
        for (int idx = tid; idx < 3200; idx += 256) smem[idx] = src[idx];
        __syncthreads();
        for (int idx = tid; idx < 3200; idx += 256) {
            int ic = idx & 127, kpos = idx >> 7;
            dst[swz(oc, kpos * 128 + ic, 100)] = f2bf(smem[ic * 25 + kpos]);
        }
    } else {
        int e = (bid - 1506) * 256 + tid;   // [0, 131072)
        if (e < 32768) {
            int oc = e >> 7, k = e & 127;
            C4Bs[swz(oc, k, 4)] = f2bf(c4w[e]);
        } else if (e < 65536) {
            int e2 = e - 32768;
            int oc = e2 >> 8, k = e2 & 255;
            C5Bs[swz(oc, k, 8)] = f2bf(c5w[e2]);
        } else {
            int e2 = e - 65536;
            int oc = e2 >> 7, k = e2 & 127;
            DWBs[swz(oc, k, 4)] = f2bf(dw[e2]);
        }
    }
}

// K2: conv2 via MFMA, swizzled W2 -> Z2[ph][A][B][oc]
__global__ __launch_bounds__(256) void k_conv2(const unsigned short* __restrict__ P2,
                                               const unsigned short* __restrict__ W2s,
                                               const float* __restrict__ bias,
                                               unsigned short* __restrict__ Z2) {
    int bid = blockIdx.x;          // 168 = 4ph * 21A * 2oh
    int ph = bid / 42;
    int rem = bid % 42;
    int A = rem >> 1;
    int oh = rem & 1;
    int tid = threadIdx.x, lane = tid & 63, wid = tid >> 6;
    int m = lane & 15, bq = lane >> 4;
    int oc0 = oh * 64 + wid * 16;
    int t = oh * 4 + wid;                      // oc tile index
    const unsigned short* wbase = W2s + (t * 100 * 64 + lane) * 8;
    const unsigned short* pbase = P2 + ((ph * 25 + A) * 25) * 128 + 8 * bq;
    f32x4 acc0 = {0.f, 0.f, 0.f, 0.f}, acc1 = {0.f, 0.f, 0.f, 0.f};
    for (int kpos = 0; kpos < 25; ++kpos) {
        int ky = kpos / 5, kx = kpos % 5;
        const unsigned short* wp = wbase + kpos * 4 * 512;
        const unsigned short* p0 = pbase + (ky * 25 + m + kx) * 128;
        const unsigned short* p1 = p0 + 5 * 128;
#pragma unroll
        for (int cc = 0; cc < 4; ++cc) {
            short8 a  = *(const short8*)(wp + cc * 512);
            short8 b0 = *(const short8*)(p0 + cc * 32);
            short8 b1 = *(const short8*)(p1 + cc * 32);
            acc0 = __builtin_amdgcn_mfma_f32_16x16x32_bf16(a, b0, acc0, 0, 0, 0);
            acc1 = __builtin_amdgcn_mfma_f32_16x16x32_bf16(a, b1, acc1, 0, 0, 0);
        }
    }
    int ocb = oc0 + 4 * bq;
    float b0v = bias[ocb], b1v = bias[ocb + 1], b2v = bias[ocb + 2], b3v = bias[ocb + 3];
    unsigned short* zrow = Z2 + ((ph * 21 + A) * 21) * 128 + ocb;
    {
        ushort4 pk;
        pk.x = f2bf(lrelu(acc0.x + b0v));
        pk.y = f2bf(lrelu(acc0.y + b1v));
        pk.z = f2bf(lrelu(acc0.z + b2v));
        pk.w = f2bf(lrelu(acc0.w + b3v));
        *(ushort4*)(zrow + m * 128) = pk;          // B = m (0..15)
    }
    if (m >= 11) {                                 // B = m+5 (16..20)
        ushort4 pk;
        pk.x = f2bf(lrelu(acc1.x + b0v));
        pk.y = f2bf(lrelu(acc1.y + b1v));
        pk.z = f2bf(lrelu(acc1.z + b2v));
        pk.w = f2bf(lrelu(acc1.w + b3v));
        *(ushort4*)(zrow + (m + 5) * 128) = pk;
    }
}

// K3: 16-phase second pool -> Q2[qph][C][D][ic]  (wide, 1 elem/thread)
__global__ __launch_bounds__(256) void k_pool2(const unsigned short* __restrict__ Z2,
                                               unsigned short* __restrict__ Q2) {
    int t = blockIdx.x * 256 + threadIdx.x;   // 204800
    int ic = t & 127;
    int rest = t >> 7;
    int D = rest % 10;
    int C = (rest / 10) % 10;
    int qph = rest / 100;
    int iq = qph >> 2, jq = qph & 3;
    int ph1 = (iq & 1) * 2 + (jq & 1);
    int py2 = iq >> 1, px2 = jq >> 1;
    int r0 = 2 * C + py2, s0 = 2 * D + px2;
    const unsigned short* z00 = Z2 + ((ph1 * 21 + r0) * 21 + s0) * 128 + ic;
    float m0 = fmaxf(bf2f(z00[0]), bf2f(z00[128]));
    float m1 = fmaxf(bf2f(z00[21 * 128]), bf2f(z00[22 * 128]));
    Q2[t] = f2bf(fmaxf(m0, m1));
}

// K4: conv3 + conv4 + conv5 + dense, all MFMA, B-fragments direct from Q2 (L2).
// 36 blocks x 512 threads (8 waves), 16 patches per block. LDS ~17 KB.
__global__ __launch_bounds__(512) void k_tail3(const unsigned short* __restrict__ Q2,
                                               const unsigned short* __restrict__ W3s,
                                               const float* __restrict__ c3b,
                                               const unsigned short* __restrict__ C4Bs,
                                               const float* __restrict__ c4b,
                                               const unsigned short* __restrict__ C5Bs,
                                               const float* __restrict__ c5b,
                                               const unsigned short* __restrict__ DWBs,
                                               const float* __restrict__ db,
                                               float* __restrict__ out) {
    __shared__ unsigned short h3bf[16 * 136];
    __shared__ unsigned short h4bf[16 * 264];
    __shared__ unsigned short h5bf[16 * 136];

    int bid = blockIdx.x, tid = threadIdx.x;
    int n0 = bid * 16;
    int lane = tid & 63, w = tid >> 6;          // 8 waves
    int m = lane & 15, bq = lane >> 4;

    // ---- conv3: wave w -> oc tile [16w,16w+16), cols = 16 patches; B from Q2 ----
    {
        int p = n0 + m;
        int i = p / 24, j = p % 24;
        int qph = (i & 3) * 4 + (j & 3);
        int C0 = i >> 2, D0 = j >> 2;
        const unsigned short* qbase = Q2 + qph * 12800 + (C0 * 10 + D0) * 128 + 8 * bq;
        const unsigned short* wbase = W3s + (w * 100 * 64 + lane) * 8;
        f32x4 acc = {0.f, 0.f, 0.f, 0.f};
        for (int kpos = 0; kpos < 25; ++kpos) {
            int e = kpos / 5, f = kpos % 5;
            const unsigned short* qp = qbase + (e * 10 + f) * 128;
            const unsigned short* wp = wbase + kpos * 4 * 512;
#pragma unroll
            for (int cc = 0; cc < 4; ++cc) {
                short8 a = *(const short8*)(wp + cc * 512);
                short8 b = *(const short8*)(qp + cc * 32);
                acc = __builtin_amdgcn_mfma_f32_16x16x32_bf16(a, b, acc, 0, 0, 0);
            }
        }
        int oc = w * 16 + bq * 4;
        float v0 = lrelu(acc.x + c3b[oc + 0]);
        float v1 = lrelu(acc.y + c3b[oc + 1]);
        float v2 = lrelu(acc.z + c3b[oc + 2]);
        float v3 = lrelu(acc.w + c3b[oc + 3]);
        uint2 pk;
        pk.x = (unsigned)f2bf(v0) | ((unsigned)f2bf(v1) << 16);
        pk.y = (unsigned)f2bf(v2) | ((unsigned)f2bf(v3) << 16);
        *(uint2*)(&h3bf[m * 136 + oc]) = pk;
    }
    __syncthreads();

    // ---- conv4: wave w -> oc tiles {w*2, w*2+1} (32 oc), K=128 ----
    {
        f32x4 acc[2] = {{0,0,0,0},{0,0,0,0}};
#pragma unroll
        for (int t = 0; t < 2; ++t) {
            const unsigned short* abase = C4Bs + (((w * 2 + t) * 4) * 64 + lane) * 8;
#pragma unroll
            for (int cc = 0; cc < 4; ++cc) {
                short8 a = *(const short8*)(abase + cc * 512);
                short8 b = *(const short8*)(&h3bf[m * 136 + cc * 32 + 8 * bq]);
                acc[t] = __builtin_amdgcn_mfma_f32_16x16x32_bf16(a, b, acc[t], 0, 0, 0);
            }
        }
#pragma unroll
        for (int t = 0; t < 2; ++t) {
            int oc = (w * 2 + t) * 16 + bq * 4;
            float v0 = lrelu(acc[t].x + c4b[oc + 0]);
            float v1 = lrelu(acc[t].y + c4b[oc + 1]);
            float v2 = lrelu(acc[t].z + c4b[oc + 2]);
            float v3 = lrelu(acc[t].w + c4b[oc + 3]);
            uint2 pk;
            pk.x = (unsigned)f2bf(v0) | ((unsigned)f2bf(v1) << 16);
            pk.y = (unsigned)f2bf(v2) | ((unsigned)f2bf(v3) << 16);
            *(uint2*)(&h4bf[m * 264 + oc]) = pk;
        }
    }
    __syncthreads();

    // ---- conv5: wave w -> oc tile w (16 oc), K=256 ----
    {
        const unsigned short* abase = C5Bs + ((w * 8) * 64 + lane) * 8;
        f32x4 acc = {0.f, 0.f, 0.f, 0.f};
#pragma unroll
        for (int cc = 0; cc < 8; ++cc) {
            short8 a = *(const short8*)(abase + cc * 512);
            short8 b = *(const short8*)(&h4bf[m * 264 + cc * 32 + 8 * bq]);
            acc = __builtin_amdgcn_mfma_f32_16x16x32_bf16(a, b, acc, 0, 0, 0);
        }
        int oc = w * 16 + bq * 4;
        float v0 = lrelu(acc.x + c5b[oc + 0]);
        float v1 = lrelu(acc.y + c5b[oc + 1]);
        float v2 = lrelu(acc.z + c5b[oc + 2]);
        float v3 = lrelu(acc.w + c5b[oc + 3]);
        uint2 pk;
        pk.x = (unsigned)f2bf(v0) | ((unsigned)f2bf(v1) << 16);
        pk.y = (unsigned)f2bf(v2) | ((unsigned)f2bf(v3) << 16);
        *(uint2*)(&h5bf[m * 136 + oc]) = pk;
    }
    __syncthreads();

    // ---- dense: wave w -> oc tiles {w*4..w*4+3} (64 oc), K=128 ----
    {
        f32x4 acc[4] = {{0,0,0,0},{0,0,0,0},{0,0,0,0},{0,0,0,0}};
#pragma unroll
        for (int t = 0; t < 4; ++t) {
            const unsigned short* abase = DWBs + (((w * 4 + t) * 4) * 64 + lane) * 8;
#pragma unroll
            for (int cc = 0; cc < 4; ++cc) {
                short8 a = *(const short8*)(abase + cc * 512);
                short8 b = *(const short8*)(&h5bf[m * 136 + cc * 32 + 8 * bq]);
                acc[t] = __builtin_amdgcn_mfma_f32_16x16x32_bf16(a, b, acc[t], 0, 0, 0);
            }
        }
#pragma unroll
        for (int t = 0; t < 4; ++t) {
            int oc = (w * 4 + t) * 16 + bq * 4;
            out[(oc + 0) * 576 + n0 + m] = acc[t].x + db[oc + 0];
            out[(oc + 1) * 576 + n0 + m] = acc[t].y + db[oc + 1];
            out[(oc + 2) * 576 + n0 + m] = acc[t].z + db[oc + 2];
            out[(oc + 3) * 576 + n0 + m] = acc[t].w + db[oc + 3];
        }
    }
}

extern "C" void kernel_launch(void* const* d_in, const int* in_sizes, int n_in,
                              void* d_out, int out_size, void* d_ws, size_t ws_size,
                              hipStream_t stream) {
    const float* x   = (const float*)d_in[0];
    const float* c1w = (const float*)d_in[1];
    const float* c1b = (const float*)d_in[2];
    const float* c2w = (const float*)d_in[3];
    const float* c2b = (const float*)d_in[4];
    const float* c3w = (const float*)d_in[5];
    const float* c3b = (const float*)d_in[6];
    const float* c4w = (const float*)d_in[7];
    const float* c4b = (const float*)d_in[8];
    const float* c5w = (const float*)d_in[9];
    const float* c5b = (const float*)d_in[10];
    const float* dw  = (const float*)d_in[11];
    const float* db  = (const float*)d_in[12];
    float* out = (float*)d_out;

    float* ws = (float*)d_ws;
    unsigned short* P2   = (unsigned short*)(ws);            // 160000 f32 slots
    unsigned short* Z2   = (unsigned short*)(ws + 160000);   // 112896
    unsigned short* W2s  = (unsigned short*)(ws + 272896);   // 204800
    unsigned short* W3s  = (unsigned short*)(ws + 477696);   // 204800
    unsigned short* C4Bs = (unsigned short*)(ws + 682496);   // 16384
    unsigned short* C5Bs = (unsigned short*)(ws + 698880);   // 16384
    unsigned short* DWBs = (unsigned short*)(ws + 715264);   // 32768
    unsigned short* Q2   = (unsigned short*)(ws + 748032);   // 102400

    k_front<<<2018, 256, 0, stream>>>(x, c1w, c1b, c2w, c3w, c4w, c5w, dw,
                                      P2, W2s, W3s, C4Bs, C5Bs, DWBs);
    k_conv2<<<168, 256, 0, stream>>>(P2, W2s, c2b, Z2);
    k_pool2<<<800, 256, 0, stream>>>(Z2, Q2);
    k_tail3<<<36, 512, 0, stream>>>(Q2, W3s, c3b, C4Bs, c4b, C5Bs, c5b, DWBs, db, out);
}